// Round 5
// baseline (268.742 us; speedup 1.0000x reference)
//
#include <hip/hip_runtime.h>
#include <hip/hip_bf16.h>
#include <math.h>

#define Tn   8192
#define Hn   1024
#define En   8
#define DFFn 4096

typedef __attribute__((ext_vector_type(8))) short bf16x8;           // 8 bf16 = 4 VGPRs
typedef __attribute__((ext_vector_type(8))) unsigned short u16x8;   // 16 B
typedef __attribute__((ext_vector_type(4))) float f32x4;

static __device__ inline unsigned short f2bf(float f) {
    __hip_bfloat16 h = __float2bfloat16(f);
    return __builtin_bit_cast(unsigned short, h);
}

// ---------------- prep (unchanged from r3) --------------------------------
__global__ __launch_bounds__(256) void prep(
    const float* __restrict__ W1, unsigned short* __restrict__ W1t,
    const float* __restrict__ W2, unsigned short* __restrict__ W2t,
    const float* __restrict__ x, const float* __restrict__ gW,
    const float* __restrict__ gb, unsigned short* __restrict__ xbf,
    float* __restrict__ tokw, float* __restrict__ load_sum,
    int* __restrict__ counts)
{
    __shared__ float smem[8 * 1024 + En];
    __shared__ int   s_cnt[En];
    const int tid = threadIdx.x;
    const int id  = blockIdx.x;

    if (id < 512) {  // ---- fat transpose+cast ----
        const float* src; unsigned short* dst; int SR, SC, tb;
        if (id < 256) { src = W1; dst = W1t; SR = Hn;   SC = DFFn; tb = id; }
        else          { src = W2; dst = W2t; SR = DFFn; SC = Hn;   tb = id - 256; }
        const int tcs = SC >> 7;
        const int tr  = tb / tcs, tc = tb - tr * tcs;
        const int r0  = tr << 7, c0 = tc << 7;
        unsigned short* tile = (unsigned short*)smem;   // [128][128] swizzled

        #pragma unroll
        for (int i = 0; i < 16; ++i) {
            int idx = tid + i * 256;
            int r = idx >> 5, c4 = (idx & 31) << 2;
            float4 v = *(const float4*)(src + (size_t)(r0 + r) * SC + c0 + c4);
            int cs = c4 ^ (((r >> 3) & 7) << 2);
            ushort4 pk;
            pk.x = f2bf(v.x); pk.y = f2bf(v.y);
            pk.z = f2bf(v.z); pk.w = f2bf(v.w);
            *(ushort4*)(tile + r * 128 + cs) = pk;
        }
        __syncthreads();
        #pragma unroll
        for (int i = 0; i < 8; ++i) {
            int idx = tid + i * 256;
            int n = idx >> 4, kg = idx & 15, k0 = kg << 3;
            int s = (kg & 7) << 2;
            u16x8 o;
            #pragma unroll
            for (int j = 0; j < 8; ++j)
                o[j] = tile[(k0 + j) * 128 + (n ^ s)];
            *(u16x8*)(dst + (size_t)(c0 + n) * SR + r0 + k0) = o;
        }
        return;
    }

    // ---- gate + x cast ----
    const int gid = id - 512;
    float* gwt    = smem;
    float* s_load = smem + 8 * 1024;
    if (tid < En) { s_load[tid] = 0.f; s_cnt[tid] = 0; }
    #pragma unroll
    for (int i = 0; i < 32; ++i) {
        int f = tid + i * 256;
        gwt[(f & 7) * 1024 + (f >> 3)] = gW[f];
    }
    __syncthreads();

    const int lane = tid & 63;
    const int wv   = tid >> 6;

    for (int tok = gid * 4 + wv; tok < Tn; tok += 4096) {
        const float4* xr = (const float4*)(x + (size_t)tok * Hn);
        float acc[8] = {0.f,0.f,0.f,0.f,0.f,0.f,0.f,0.f};
        #pragma unroll
        for (int j = 0; j < Hn / 256; ++j) {
            int h4 = j * 64 + lane;
            float4 xv = xr[h4];
            ushort4 pk;
            pk.x = f2bf(xv.x); pk.y = f2bf(xv.y);
            pk.z = f2bf(xv.z); pk.w = f2bf(xv.w);
            ((ushort4*)xbf)[(size_t)tok * (Hn / 4) + h4] = pk;
            #pragma unroll
            for (int e = 0; e < 8; ++e) {
                const float4 w = *(const float4*)(gwt + e * 1024 + h4 * 4);
                acc[e] += xv.x * w.x + xv.y * w.y + xv.z * w.z + xv.w * w.w;
            }
        }
        #pragma unroll
        for (int e = 0; e < 8; ++e) {
            float v = acc[e];
            #pragma unroll
            for (int off = 32; off > 0; off >>= 1) v += __shfl_xor(v, off, 64);
            acc[e] = v + gb[e];
        }
        if (lane == 0) {
            #pragma unroll
            for (int e = 0; e < 8; ++e) atomicAdd(&s_load[e], acc[e]);
            int i1 = 0; float v1 = acc[0];
            #pragma unroll
            for (int e = 1; e < 8; ++e) if (acc[e] > v1) { v1 = acc[e]; i1 = e; }
            int i2 = -1; float v2 = -3.0e38f;
            #pragma unroll
            for (int e = 0; e < 8; ++e) if (e != i1 && acc[e] > v2) { v2 = acc[e]; i2 = e; }
            atomicAdd(&s_cnt[i1], 1);
            atomicAdd(&s_cnt[i2], 1);
            float e2 = __expf(v2 - v1);
            float t  = 1.0f + e2;
            tokw[tok] = 1.0f / t + e2 / t;
        }
    }
    __syncthreads();
    if (tid < En) {
        atomicAdd(&load_sum[tid], s_load[tid]);
        atomicAdd(&counts[tid],   s_cnt[tid]);
    }
}

// =================== cross-phase pipelined 256-wide GEMM ==================
// r5: reads for phase p+1 issued during phase p -> the LDS drain (~48
// b128/CU/phase) runs UNDER the MFMA cluster instead of alternating with it
// (r4 falsified the in-phase ladder; only cross-phase shift overlaps).
//
// G0 (BN=256, WM=2, WN=4): B-reads shifted one phase early (bfr slots
//   provably dead in issuing phase -> zero extra VGPR); af reads stay
//   in-phase (half-split would cost +32 VGPR against a ~248/256 budget).
//   Ledger (stages as r1; FIFO per wave):
//     pro: 14 loads, vmcnt(6) [buf0 done], barrier, pre-read bfr01-buf0.
//     drains: vmcnt(4) at END of P2 and P6 (+barrier) => buf1 complete
//       before P3's bfr-buf1 reads / buf0' complete before P7's reads.
//     every stage lands >=2 phases after its region's last read-issue:
//       S(P1)=A02: af-h0 read@P0 (in-phase, drained by WAITL(4)@P0);
//       S(P2/P3)=B: rows read @P7-prev/@P0, complete @P0/@P1; S(P4)=A13:
//       af-h1@P2; S(P5)=A02(buf1): af@P4; S(P6/P7)=B(buf1): reads @P3/@P4.
// G1 (BN=128, WM=4, WN=2): FULL pipeline, separate reg sets afh0/afh1/
//   bfrS0/bfrS1 (+48 VGPR, safe: acc only 64).
//     pro: 12 loads (buf0 6 first, buf1 6), vmcnt(6) [buf0 done], barrier,
//       pre-read R(P0) = afh0+bfrS0 (12).
//     P0: R(P1)=afh1(4); WAITL(0); MFMA h0; vmcnt(0) [buf1: loads >=2
//         phases old]; bar.
//     P1: R(P2)=afh0'+bfrS1 (12, buf1); stage 6 (buf0<-c2: B01+A0-3);
//         WAITL(12); MFMA h1; bar.
//     P2: R(P3)=afh1'(4, buf1); WAITL(0) [drains R(P2),R(P3) -> S(P3)
//         formally safe]; MFMA h0(buf1); vmcnt(0) [buf0' complete, loads
//         2 phases old]; bar.
//     P3: R(P0')=12 (buf0'); stage 6 (buf1<-c3); WAITL(12); MFMA h1; bar.
static __device__ inline bf16x8 ldsfrag(const char* base, int row, int chunk) {
    return *(const bf16x8*)(base + row * 128 + (((chunk) ^ (row & 7)) << 4));
}

template<int BN, int WM, int WN, int EPI>
__global__ __launch_bounds__(512, 2) void gemm8(
    const __hip_bfloat16* __restrict__ A,
    const __hip_bfloat16* __restrict__ Bt,
    const float* __restrict__ bias,
    const float* __restrict__ tokw,
    void* __restrict__ C, int N, int K, int nx,
    const float* __restrict__ load_sum, const int* __restrict__ counts,
    float* __restrict__ out_tail, int nblk)
{
    constexpr int BM = 256;
    constexpr int MR = (BM / WM) / 16;        // 8 (G0) or 4 (G1)
    constexpr int NR = (BN / WN) / 16;        // 4
    constexpr int AU = BM / 64;               // 4 stage units (8 KB each)
    constexpr int BU = BN / 64;               // 4 (G0) or 2 (G1)
    constexpr int ABYTES = BM * 64 * 2;       // 32 KB
    constexpr int BBYTES = BN * 64 * 2;       // 32/16 KB
    constexpr int TILEB  = ABYTES + BBYTES;

    extern __shared__ char lds[];

    const int tid = threadIdx.x;
    const int id  = blockIdx.x;

    if (EPI == 0 && id >= nblk) {   // ---- aux-loss / counts tail block ----
        if (tid == 0) {
            float aux = 0.f;
            #pragma unroll
            for (int e = 0; e < En; ++e) {
                float m = load_sum[e] * (1.0f / (float)Tn);
                aux += m * m;
            }
            out_tail[0] = aux;
            #pragma unroll
            for (int e = 0; e < En; ++e) out_tail[1 + e] = (float)counts[e];
        }
        return;
    }

    // bijective XCD swizzle (nblk % 8 == 0)
    int wg = id;
    { int xcd = wg & 7, idx = wg >> 3; wg = xcd * (nblk >> 3) + idx; }
    const int by = wg / nx, bx = wg % nx;
    const int m0 = by * BM, n0 = bx * BN;

    const int lane = tid & 63;
    const int wid  = tid >> 6;
    const int wn   = wid % WN;
    const int wm   = wid / WN;
    const int wrow = wm * (BM / WM);
    const int wcol = wn * (BN / WN);
    const int fr   = lane & 15;
    const int fq   = lane >> 4;

    const int sr = tid >> 3;
    const int sc = (tid & 7) ^ (sr & 7);
    unsigned aOff[AU], bOff[BU];
    #pragma unroll
    for (int u = 0; u < AU; ++u)
        aOff[u] = (unsigned)((m0 + u * 64 + sr) * K + sc * 8);
    #pragma unroll
    for (int u = 0; u < BU; ++u)
        bOff[u] = (unsigned)((n0 + u * 64 + sr) * K + sc * 8);

#define STA(b, u, kt) __builtin_amdgcn_global_load_lds( \
    (const __attribute__((address_space(1))) void*)(A + aOff[u] + (unsigned)(kt) * 64u), \
    (__attribute__((address_space(3))) void*)(lds + (b) * TILEB + (u) * 8192 + tid * 16), 16, 0, 0)
#define STB(b, u, kt) __builtin_amdgcn_global_load_lds( \
    (const __attribute__((address_space(1))) void*)(Bt + bOff[u] + (unsigned)(kt) * 64u), \
    (__attribute__((address_space(3))) void*)(lds + (b) * TILEB + ABYTES + (u) * 8192 + tid * 16), 16, 0, 0)

#define SBAR do { \
    __builtin_amdgcn_sched_barrier(0); \
    __builtin_amdgcn_s_barrier(); \
    __builtin_amdgcn_sched_barrier(0); } while (0)
#define WAITL(n) do { \
    asm volatile("s_waitcnt lgkmcnt(" #n ")" ::: "memory"); \
    __builtin_amdgcn_sched_barrier(0); } while (0)
#define VMC(n) do { asm volatile("s_waitcnt vmcnt(" #n ")" ::: "memory"); \
    __builtin_amdgcn_sched_barrier(0); } while (0)
#define PRIO1 __builtin_amdgcn_s_setprio(1)
#define PRIO0 __builtin_amdgcn_s_setprio(0)

    const int KT = K >> 6;

    if constexpr (WM == 2) {
        // ================= G0: 8-phase, B-reads shifted =================
        bf16x8 af[4][2];     // current A half (in-phase reads)
        bf16x8 bfr[4][2];    // B frags (pipelined one phase ahead)
        f32x4  acc[8][4];
        const f32x4 zero = {0.f, 0.f, 0.f, 0.f};
        #pragma unroll
        for (int i = 0; i < 8; ++i)
            #pragma unroll
            for (int j = 0; j < 4; ++j) acc[i][j] = zero;

#define RD_A(b, half) do { _Pragma("unroll") \
    for (int m_ = 0; m_ < 4; ++m_) { _Pragma("unroll") \
        for (int ks_ = 0; ks_ < 2; ++ks_) \
            af[m_][ks_] = ldsfrag(lds + (b) * TILEB, \
                wrow + ((half) * 4 + m_) * 16 + fr, ks_ * 4 + fq); } } while (0)
#define RD_B(b, nn) do { _Pragma("unroll") \
    for (int ks_ = 0; ks_ < 2; ++ks_) \
        bfr[nn][ks_] = ldsfrag(lds + (b) * TILEB + ABYTES, \
            wcol + (nn) * 16 + fr, ks_ * 4 + fq); } while (0)
#define MFMAQ(hm, hn) do { \
    PRIO1; \
    _Pragma("unroll") \
    for (int m_ = 0; m_ < 4; ++m_) { _Pragma("unroll") \
        for (int n_ = 0; n_ < 2; ++n_) { _Pragma("unroll") \
            for (int ks_ = 0; ks_ < 2; ++ks_) \
                acc[(hm) * 4 + m_][(hn) * 2 + n_] = \
                    __builtin_amdgcn_mfma_f32_16x16x32_bf16( \
                        af[m_][ks_], bfr[(hn) * 2 + n_][ks_], \
                        acc[(hm) * 4 + m_][(hn) * 2 + n_], 0, 0, 0); } } \
    PRIO0; } while (0)

        // prologue: buf0 full + buf1 minus A{1,3}
        STA(0,0,0); STA(0,1,0); STA(0,2,0); STA(0,3,0);
        STB(0,0,0); STB(0,1,0); STB(0,2,0); STB(0,3,0);
        STA(1,0,1); STA(1,2,1);
        STB(1,0,1); STB(1,1,1); STB(1,2,1); STB(1,3,1);
        VMC(6);
        __builtin_amdgcn_s_barrier();
        __builtin_amdgcn_sched_barrier(0);
        RD_B(0,0); RD_B(0,1);      // pre-read bfr01 for P0 (4 reads)

        for (int i = 0; i < (KT >> 1); ++i) {
            const int t1 = 2 * i + 1;
            const int c2 = (2 * i + 2 < KT) ? 2 * i + 2 : KT - 1;
            const int c3 = (2 * i + 3 < KT) ? 2 * i + 3 : KT - 1;

            // P0: MFMA Q(0,0) [af-h0 x bfr01]; in-phase af-h0; shift bfr23
            RD_A(0,0);
            RD_B(0,2); RD_B(0,3);
            STA(1,1,t1); STA(1,3,t1);
            SBAR; WAITL(4); MFMAQ(0,0); SBAR;
            // P1: Q(0,1) [af-h0 x bfr23]
            STA(0,0,c2); STA(0,2,c2);
            SBAR; WAITL(0); MFMAQ(0,1); SBAR;
            // P2: Q(1,0) [af-h1 x bfr01]; vmcnt(4) at end -> buf1 complete
            RD_A(0,1);
            STB(0,0,c2); STB(0,1,c2);
            SBAR; WAITL(0); MFMAQ(1,0); VMC(4); SBAR;
            // P3: Q(1,1) [af-h1 x bfr23]; shift bfr01 <- buf1
            RD_B(1,0); RD_B(1,1);
            STB(0,2,c2); STB(0,3,c2);
            SBAR; WAITL(4); MFMAQ(1,1); SBAR;
            // P4: Q(0,0) buf1; in-phase af-h0(buf1); shift bfr23 <- buf1
            RD_A(1,0);
            RD_B(1,2); RD_B(1,3);
            STA(0,1,c2); STA(0,3,c2);
            SBAR; WAITL(4); MFMAQ(0,0); SBAR;
            // P5: Q(0,1) buf1
            STA(1,0,c3); STA(1,2,c3);
            SBAR; WAITL(0); MFMAQ(0,1); SBAR;
            // P6: Q(1,0) buf1; vmcnt(4) at end -> buf0(c2) complete
            RD_A(1,1);
            STB(1,0,c3); STB(1,1,c3);
            SBAR; WAITL(0); MFMAQ(1,0); VMC(4); SBAR;
            // P7: Q(1,1) buf1; shift bfr01 <- buf0 (tile 2i+2)
            RD_B(0,0); RD_B(0,1);
            STB(1,2,c3); STB(1,3,c3);
            SBAR; WAITL(4); MFMAQ(1,1); SBAR;
        }

        // epilogue: C/D layout col = lane&15, row = (lane>>4)*4 + reg
        float bias4[4];
        #pragma unroll
        for (int ni = 0; ni < 4; ++ni)
            bias4[ni] = bias[n0 + wcol + ni * 16 + fr];
        #pragma unroll
        for (int mi = 0; mi < 8; ++mi) {
            #pragma unroll
            for (int ni = 0; ni < 4; ++ni) {
                const int col = n0 + wcol + ni * 16 + fr;
                const int rb  = m0 + wrow + mi * 16 + fq * 4;
                #pragma unroll
                for (int i2 = 0; i2 < 4; ++i2) {
                    float u  = acc[mi][ni][i2] + bias4[ni];
                    float uu = u * u;
                    float z  = u * __fmaf_rn(uu, -0.07135607f, -1.59576912f);
                    float e  = __expf(z);
                    float g  = u * __builtin_amdgcn_rcpf(1.0f + e);
                    ((__hip_bfloat16*)C)[(size_t)(rb + i2) * N + col] =
                        __float2bfloat16(g);
                }
            }
        }
#undef RD_A
#undef RD_B
#undef MFMAQ
    } else {
        // ================= G1: 4-phase, fully pipelined =================
        bf16x8 afh0[2][2], afh1[2][2];       // A halves, separate sets
        bf16x8 bfrS0[4][2], bfrS1[4][2];     // B per buffer parity
        f32x4  acc[4][4];
        const f32x4 zero = {0.f, 0.f, 0.f, 0.f};
        #pragma unroll
        for (int i = 0; i < 4; ++i)
            #pragma unroll
            for (int j = 0; j < 4; ++j) acc[i][j] = zero;

#define RD_AH(dst, b, half) do { _Pragma("unroll") \
    for (int m_ = 0; m_ < 2; ++m_) { _Pragma("unroll") \
        for (int ks_ = 0; ks_ < 2; ++ks_) \
            dst[m_][ks_] = ldsfrag(lds + (b) * TILEB, \
                wrow + ((half) * 2 + m_) * 16 + fr, ks_ * 4 + fq); } } while (0)
#define RD_BS(dst, b) do { _Pragma("unroll") \
    for (int n_ = 0; n_ < 4; ++n_) { _Pragma("unroll") \
        for (int ks_ = 0; ks_ < 2; ++ks_) \
            dst[n_][ks_] = ldsfrag(lds + (b) * TILEB + ABYTES, \
                wcol + n_ * 16 + fr, ks_ * 4 + fq); } } while (0)
// swapped operands (r2): D transposed -> float4 epilogue
#define MFMAH(afx, bfx, hm) do { \
    PRIO1; \
    _Pragma("unroll") \
    for (int m_ = 0; m_ < 2; ++m_) { _Pragma("unroll") \
        for (int n_ = 0; n_ < 4; ++n_) { _Pragma("unroll") \
            for (int ks_ = 0; ks_ < 2; ++ks_) \
                acc[(hm) * 2 + m_][n_] = \
                    __builtin_amdgcn_mfma_f32_16x16x32_bf16( \
                        bfx[n_][ks_], afx[m_][ks_], \
                        acc[(hm) * 2 + m_][n_], 0, 0, 0); } } \
    PRIO0; } while (0)

        // prologue: buf0 {A0-3,B01} then buf1 {B01,A0-3} (FIFO order matters)
        STA(0,0,0); STA(0,1,0); STA(0,2,0); STA(0,3,0);
        STB(0,0,0); STB(0,1,0);
        STB(1,0,1); STB(1,1,1);
        STA(1,0,1); STA(1,1,1); STA(1,2,1); STA(1,3,1);
        VMC(6);
        __builtin_amdgcn_s_barrier();
        __builtin_amdgcn_sched_barrier(0);
        RD_AH(afh0, 0, 0); RD_BS(bfrS0, 0);      // R(P0): 12 reads

        for (int i = 0; i < (KT >> 1); ++i) {
            const int c2 = (2 * i + 2 < KT) ? 2 * i + 2 : KT - 1;
            const int c3 = (2 * i + 3 < KT) ? 2 * i + 3 : KT - 1;

            // P0: MFMA h0(buf0); issue R(P1)=afh1(buf0)
            RD_AH(afh1, 0, 1);
            SBAR; WAITL(0); MFMAH(afh0, bfrS0, 0); VMC(0); SBAR;
            // P1: MFMA h1(buf0); issue R(P2)=afh0',bfrS1 (buf1); stage buf0<-c2
            RD_AH(afh0, 1, 0); RD_BS(bfrS1, 1);
            STB(0,0,c2); STB(0,1,c2);
            STA(0,0,c2); STA(0,1,c2); STA(0,2,c2); STA(0,3,c2);
            SBAR; WAITL(12); MFMAH(afh1, bfrS0, 1); SBAR;
            // P2: MFMA h0(buf1); issue R(P3)=afh1'(buf1); drain all lgkm
            RD_AH(afh1, 1, 1);
            SBAR; WAITL(0); MFMAH(afh0, bfrS1, 0); VMC(0); SBAR;
            // P3: MFMA h1(buf1); issue R(P0')=afh0,bfrS0 (buf0=c2); stage buf1<-c3
            RD_AH(afh0, 0, 0); RD_BS(bfrS0, 0);
            STB(1,0,c3); STB(1,1,c3);
            STA(1,0,c3); STA(1,1,c3); STA(1,2,c3); STA(1,3,c3);
            SBAR; WAITL(12); MFMAH(afh1, bfrS1, 1); SBAR;
        }

        // epilogue (swapped D): M = lane&15, N = (lane>>4)*4+reg -> float4
        const int mrow0 = m0 + wrow + fr;
        const int ncol0 = n0 + wcol + fq * 4;
        float4 b4[4];
        #pragma unroll
        for (int ni = 0; ni < 4; ++ni)
            b4[ni] = *(const float4*)(bias + ncol0 + ni * 16);

        #pragma unroll
        for (int mi = 0; mi < 4; ++mi) {
            const int row = mrow0 + mi * 16;
            const float tw = tokw[row];
            #pragma unroll
            for (int ni = 0; ni < 4; ++ni) {
                f32x4 v = acc[mi][ni];
                float4 o;
                o.x = (v[0] + b4[ni].x) * tw;
                o.y = (v[1] + b4[ni].y) * tw;
                o.z = (v[2] + b4[ni].z) * tw;
                o.w = (v[3] + b4[ni].w) * tw;
                *(float4*)((float*)C + (size_t)row * N + ncol0 + ni * 16) = o;
            }
        }
#undef RD_AH
#undef RD_BS
#undef MFMAH
    }

#undef STA
#undef STB
#undef SBAR
#undef WAITL
#undef VMC
#undef PRIO1
#undef PRIO0
}

extern "C" void kernel_launch(void* const* d_in, const int* in_sizes, int n_in,
                              void* d_out, int out_size, void* d_ws, size_t ws_size,
                              hipStream_t stream)
{
    const float* x  = (const float*)d_in[0];
    const float* gW = (const float*)d_in[1];
    const float* gb = (const float*)d_in[2];
    const float* W1 = (const float*)d_in[3];
    const float* b1 = (const float*)d_in[4];
    const float* W2 = (const float*)d_in[5];
    const float* b2 = (const float*)d_in[6];
    float* out = (float*)d_out;

    char* ws = (char*)d_ws;
    __hip_bfloat16* xbf = (__hip_bfloat16*)ws;  ws += (size_t)Tn * Hn * 2;
    __hip_bfloat16* W1t = (__hip_bfloat16*)ws;  ws += (size_t)Hn * DFFn * 2;
    __hip_bfloat16* W2t = (__hip_bfloat16*)ws;  ws += (size_t)Hn * DFFn * 2;
    __hip_bfloat16* hdd = (__hip_bfloat16*)ws;  ws += (size_t)Tn * DFFn * 2;
    float* tokw     = (float*)ws;               ws += (size_t)Tn * 4;
    float* load_sum = (float*)ws;               ws += En * 4;
    int*   counts   = (int*)ws;                 ws += En * 4;

    static bool attr_done = false;
    if (!attr_done) {
        (void)hipFuncSetAttribute(
            reinterpret_cast<const void*>(&gemm8<256, 2, 4, 0>),
            hipFuncAttributeMaxDynamicSharedMemorySize, 131072);
        (void)hipFuncSetAttribute(
            reinterpret_cast<const void*>(&gemm8<128, 4, 2, 1>),
            hipFuncAttributeMaxDynamicSharedMemorySize, 98304);
        attr_done = true;
    }

    hipMemsetAsync(load_sum, 0, En * 4 * 2, stream);

    prep<<<1536, 256, 0, stream>>>(W1, (unsigned short*)W1t,
                                   W2, (unsigned short*)W2t,
                                   x, gW, gb, (unsigned short*)xbf,
                                   tokw, load_sum, counts);

    // hdd = gelu(x @ W1 + b1): M=8192, N=4096, K=1024; 32x16 = 512 tiles
    gemm8<256, 2, 4, 0><<<513, 512, 131072, stream>>>(
        xbf, W1t, b1, nullptr, hdd, DFFn, Hn, 16,
        load_sum, counts, out + (size_t)Tn * Hn, 512);

    // out = (hdd @ W2 + b2) * tokw: M=8192, N=1024, K=4096; 32x8 = 256 blocks
    gemm8<128, 4, 2, 1><<<256, 512, 98304, stream>>>(
        hdd, W2t, b2, tokw, out, Hn, DFFn, 8,
        nullptr, nullptr, nullptr, 256);
}